// Round 1
// baseline (9206.237 us; speedup 1.0000x reference)
//
#include <hip/hip_runtime.h>
#include <math.h>

namespace {

constexpr int MT = 32;     // agents per block
constexpr int NT = 128;    // threads per block (2 waves)
constexpr int HS = 260;    // LDS activation row stride (floats): 16B-aligned, %32==4
constexpr int HORIZON = 64;

__global__ __launch_bounds__(NT, 2)
void rollout_kernel(const float* __restrict__ pos0,
                    const float* __restrict__ wind,
                    const float* __restrict__ w1, const float* __restrict__ b1,
                    const float* __restrict__ w2, const float* __restrict__ b2,
                    const float* __restrict__ w3, const float* __restrict__ b3,
                    const float* __restrict__ wmu, const float* __restrict__ bmu,
                    float* __restrict__ out)
{
    __shared__ __align__(16) float hA[MT * HS];   // 33280 B activation buffer
    __shared__ float obsL[MT][14];                // obs, padded stride 14
    __shared__ float aL[MT][2];                   // actions
    __shared__ float wmuL[512];                   // wmu (256,2) staged
    __shared__ float bmuL[2];

    const int t  = threadIdx.x;
    const int n0 = t;           // this thread's 1st output neuron
    const int n1 = t + NT;      // 2nd output neuron

    for (int i = t; i < 512; i += NT) wmuL[i] = wmu[i];
    if (t < 2) bmuL[t] = bmu[t];

    // Per-agent state (threads 0..31 own one agent each)
    float px = 0.f, py = 0.f, wx = 0.f, wy = 0.f;
    float mx_s = -1e30f, sum_s = 0.f;   // online logsumexp of -8*safe_margin
    float mx_r = -1e30f, sum_r = 0.f;   // online logsumexp of +8*reach_margin
    if (t < MT) {
        const int g = blockIdx.x * MT + t;
        px = pos0[2*g];  py = pos0[2*g + 1];
        wx = wind[2*g];  wy = wind[2*g + 1];
    }

    for (int step = 0; step < HORIZON; ++step) {
        // ---- P0: observation (agent threads) ----
        if (t < MT) {
            const float dx0 = px - 1.75f, dy0 = py - 1.75f;
            const float dx1 = px - 1.75f, dy1 = py - 3.75f;
            const float dx2 = px - 3.75f, dy2 = py - 2.00f;
            obsL[t][0]  = px / 10.f;
            obsL[t][1]  = py / 10.f;
            obsL[t][2]  = (4.f - px) / 10.f;
            obsL[t][3]  = (3.f - py) / 10.f;
            obsL[t][4]  = -dx0 / 10.f;  obsL[t][5]  = -dy0 / 10.f;
            obsL[t][6]  = -dx1 / 10.f;  obsL[t][7]  = -dy1 / 10.f;
            obsL[t][8]  = -dx2 / 10.f;  obsL[t][9]  = -dy2 / 10.f;
            obsL[t][10] = sqrtf(dx0*dx0 + dy0*dy0 + 1e-9f) - 0.38f;
            obsL[t][11] = sqrtf(dx1*dx1 + dy1*dy1 + 1e-9f) - 0.42f;
            obsL[t][12] = sqrtf(dx2*dx2 + dy2*dy2 + 1e-9f) - 0.34f;
        }
        __syncthreads();

        // ---- P1: layer 1 (13 -> 256), h1 -> hA ----
        {
            float w1a[13], w1b[13];
            #pragma unroll
            for (int k = 0; k < 13; ++k) {
                w1a[k] = w1[k*256 + n0];
                w1b[k] = w1[k*256 + n1];
            }
            const float bb0 = b1[n0], bb1 = b1[n1];
            #pragma unroll 4
            for (int m = 0; m < MT; ++m) {
                float s0 = bb0, s1 = bb1;
                #pragma unroll
                for (int k = 0; k < 13; ++k) {
                    const float o = obsL[m][k];    // LDS broadcast
                    s0 = fmaf(o, w1a[k], s0);
                    s1 = fmaf(o, w1b[k], s1);
                }
                hA[m*HS + n0] = fmaxf(s0, 0.f);
                hA[m*HS + n1] = fmaxf(s1, 0.f);
            }
        }
        __syncthreads();

        // ---- P2/P3: layers 2 and 3 (256 -> 256), in-place via reg accum ----
        for (int layer = 0; layer < 2; ++layer) {
            const float* __restrict__ W  = layer ? w3 : w2;
            const float* __restrict__ Bv = layer ? b3 : b2;
            float acc0[MT], acc1[MT];
            const float bb0 = Bv[n0], bb1 = Bv[n1];
            #pragma unroll
            for (int m = 0; m < MT; ++m) { acc0[m] = bb0; acc1[m] = bb1; }

            for (int k4 = 0; k4 < 64; ++k4) {
                const int k = k4 * 4;
                float wa[4], wb[4];
                #pragma unroll
                for (int i = 0; i < 4; ++i) {
                    wa[i] = W[(k+i)*256 + n0];   // coalesced across lanes
                    wb[i] = W[(k+i)*256 + n1];
                }
                #pragma unroll
                for (int m = 0; m < MT; ++m) {
                    const float4 h = *reinterpret_cast<const float4*>(&hA[m*HS + k]); // ds_read_b128 broadcast
                    acc0[m] = fmaf(h.x, wa[0], acc0[m]);
                    acc0[m] = fmaf(h.y, wa[1], acc0[m]);
                    acc0[m] = fmaf(h.z, wa[2], acc0[m]);
                    acc0[m] = fmaf(h.w, wa[3], acc0[m]);
                    acc1[m] = fmaf(h.x, wb[0], acc1[m]);
                    acc1[m] = fmaf(h.y, wb[1], acc1[m]);
                    acc1[m] = fmaf(h.z, wb[2], acc1[m]);
                    acc1[m] = fmaf(h.w, wb[3], acc1[m]);
                }
            }
            __syncthreads();   // all reads of h_in complete
            #pragma unroll
            for (int m = 0; m < MT; ++m) {
                hA[m*HS + n0] = fmaxf(acc0[m], 0.f);
                hA[m*HS + n1] = fmaxf(acc1[m], 0.f);
            }
            __syncthreads();   // h_out complete
        }

        // ---- P4: layer 4 (256 -> 2) + clip; 4 threads per agent ----
        {
            const int m = t >> 2, q = t & 3;
            const int kb = q * 64;
            float p0 = 0.f, p1 = 0.f;
            #pragma unroll 8
            for (int k = 0; k < 64; ++k) {
                const float h = hA[m*HS + kb + k];
                p0 = fmaf(h, wmuL[(kb + k)*2 + 0], p0);
                p1 = fmaf(h, wmuL[(kb + k)*2 + 1], p1);
            }
            p0 += __shfl_xor(p0, 1);  p1 += __shfl_xor(p1, 1);
            p0 += __shfl_xor(p0, 2);  p1 += __shfl_xor(p1, 2);
            if (q == 0) {
                aL[m][0] = fminf(fmaxf(p0 + bmuL[0], -1.f), 1.f);
                aL[m][1] = fminf(fmaxf(p1 + bmuL[1], -1.f), 1.f);
            }
        }
        __syncthreads();

        // ---- P5: dynamics (4 substeps) + STREL margin accumulation ----
        if (t < MT) {
            const float vx = 2.f * aL[t][0] + wx;
            const float vy = 2.f * aL[t][1] + wy;
            #pragma unroll
            for (int s = 0; s < 4; ++s) {
                px = fminf(fmaxf(px + 0.0625f * vx, -4.f), 10.f);
                py = fminf(fmaxf(py + 0.0625f * vy, -4.f), 10.f);
            }
            const float dx0 = px - 1.75f, dy0 = py - 1.75f;
            const float dx1 = px - 1.75f, dy1 = py - 3.75f;
            const float dx2 = px - 3.75f, dy2 = py - 2.00f;
            const float c0 = sqrtf(dx0*dx0 + dy0*dy0 + 1e-9f) - 0.38f;
            const float c1 = sqrtf(dx1*dx1 + dy1*dy1 + 1e-9f) - 0.42f;
            const float c2 = sqrtf(dx2*dx2 + dy2*dy2 + 1e-9f) - 0.34f;
            // spatial smooth-min (beta=50), max-shifted exactly like jax logsumexp
            const float cmin = fminf(c0, fminf(c1, c2));
            const float ssum = expf(-50.f*(c0 - cmin)) + expf(-50.f*(c1 - cmin))
                             + expf(-50.f*(c2 - cmin));
            const float safe = cmin - logf(ssum) / 50.f;
            const float gdx = px - 4.f, gdy = py - 3.f;
            const float reach = 0.45f - sqrtf(gdx*gdx + gdy*gdy + 1e-9f);
            // online logsumexp updates (exact, running max)
            const float xs = -8.f * safe;
            if (xs > mx_s) { sum_s = sum_s * expf(mx_s - xs) + 1.f; mx_s = xs; }
            else           { sum_s += expf(xs - mx_s); }
            const float xr = 8.f * reach;
            if (xr > mx_r) { sum_r = sum_r * expf(mx_r - xr) + 1.f; mx_r = xr; }
            else           { sum_r += expf(xr - mx_r); }
        }
        // no barrier needed: next P0 touches only agent-thread state; obsL/hA
        // hazards are covered by the barriers above
    }

    // ---- epilogue: rho = smoothmin8(rho_safe, rho_reach) ----
    if (t < MT) {
        const float rs = -(mx_s + logf(sum_s)) * 0.125f;   // -lse/8
        const float rr =  (mx_r + logf(sum_r)) * 0.125f;   // +lse/8
        const float u0 = -8.f * rs, u1 = -8.f * rr;
        const float mu = fmaxf(u0, u1);
        const float rho = -(mu + logf(expf(u0 - mu) + expf(u1 - mu))) * 0.125f;
        out[blockIdx.x * MT + t] = rho;
    }
}

} // namespace

extern "C" void kernel_launch(void* const* d_in, const int* in_sizes, int n_in,
                              void* d_out, int out_size, void* d_ws, size_t ws_size,
                              hipStream_t stream)
{
    const float* pos0 = (const float*)d_in[0];
    const float* wind = (const float*)d_in[1];
    const float* w1   = (const float*)d_in[2];
    const float* b1   = (const float*)d_in[3];
    const float* w2   = (const float*)d_in[4];
    const float* b2   = (const float*)d_in[5];
    const float* w3   = (const float*)d_in[6];
    const float* b3   = (const float*)d_in[7];
    const float* wmu  = (const float*)d_in[8];
    const float* bmu  = (const float*)d_in[9];
    float* out = (float*)d_out;

    const int B = in_sizes[0] / 2;          // 32768 agents
    const int blocks = B / MT;              // 1024 blocks, 4 per CU
    rollout_kernel<<<blocks, NT, 0, stream>>>(pos0, wind, w1, b1, w2, b2,
                                              w3, b3, wmu, bmu, out);
}

// Round 2
// 6275.685 us; speedup vs baseline: 1.4670x; 1.4670x over previous
//
#include <hip/hip_runtime.h>
#include <math.h>

typedef _Float16 f16;
typedef _Float16 f16x8 __attribute__((ext_vector_type(8)));
typedef float f32x4 __attribute__((ext_vector_type(4)));

namespace {

constexpr int NT = 256;     // threads per block (4 waves)
constexpr int M  = 64;      // agents per block
constexpr int HORIZON = 64;

// packed weight layout offsets in f16 units (inside d_ws)
// layout per matrix: [(kc*16 + ntile)*64 + lane]*8 + j   (B-fragment lane order)
constexpr int W1H = 0,      W1L = 8192;      // 16x256 (K padded 13->32, 1 kc)
constexpr int W2H = 16384,  W2L = 81920;     // 256x256, 8 kc
constexpr int W3H = 147456, W3L = 212992;

// ---------------- weight pre-split + pre-swizzle ----------------
__global__ void prep_kernel(const float* __restrict__ w1,
                            const float* __restrict__ w2,
                            const float* __restrict__ w3,
                            f16* __restrict__ out)
{
    int tid = blockIdx.x * blockDim.x + threadIdx.x;   // 544*256 = 139264 exact
    float v; int hi_off, lo_off;
    if (tid < 8192) {            // w1 (kc = 0 only, k>=13 zero-padded)
        int nt = tid >> 9, li = (tid >> 3) & 63, j = tid & 7;
        int k = ((li >> 4) << 3) + j, n = (nt << 4) + (li & 15);
        v = (k < 13) ? w1[k*256 + n] : 0.f;
        hi_off = W1H + tid; lo_off = W1L + tid;
    } else if (tid < 73728) {    // w2
        int e = tid - 8192;
        int kc = e >> 13, e2 = e & 8191;
        int nt = e2 >> 9, li = (e2 >> 3) & 63, j = e2 & 7;
        int k = (kc << 5) + ((li >> 4) << 3) + j, n = (nt << 4) + (li & 15);
        v = w2[k*256 + n];
        hi_off = W2H + e; lo_off = W2L + e;
    } else {                     // w3
        int e = tid - 73728;
        int kc = e >> 13, e2 = e & 8191;
        int nt = e2 >> 9, li = (e2 >> 3) & 63, j = e2 & 7;
        int k = (kc << 5) + ((li >> 4) << 3) + j, n = (nt << 4) + (li & 15);
        v = w3[k*256 + n];
        hi_off = W3H + e; lo_off = W3L + e;
    }
    f16 h = (f16)v;
    f16 l = (f16)(v - (float)h);   // exact residual -> fp32-equivalent 3-term MFMA
    out[hi_off] = h;
    out[lo_off] = l;
}

__device__ __forceinline__ void mfma3(f32x4& acc, f16x8 ah, f16x8 al, f16x8 bh, f16x8 bl)
{
    acc = __builtin_amdgcn_mfma_f32_16x16x32_f16(ah, bh, acc, 0, 0, 0);
    acc = __builtin_amdgcn_mfma_f32_16x16x32_f16(al, bh, acc, 0, 0, 0);
    acc = __builtin_amdgcn_mfma_f32_16x16x32_f16(ah, bl, acc, 0, 0, 0);
}

// ---------------- main persistent rollout ----------------
__global__ __launch_bounds__(NT, 2)
void rollout_kernel(const float* __restrict__ pos0, const float* __restrict__ wind,
                    const float* __restrict__ b1, const float* __restrict__ b2,
                    const float* __restrict__ b3, const float* __restrict__ wmu,
                    const float* __restrict__ bmu, const f16* __restrict__ wp,
                    float* __restrict__ out)
{
    // activations, fp16 hi/lo, XOR-chunk-swizzled: elem (row,k) at
    // row*256 + ((k>>3)^(row&31))*8 + (k&7)
    __shared__ __align__(16) f16 hA_hi[M*256];    // 32 KB
    __shared__ __align__(16) f16 hA_lo[M*256];    // 32 KB
    __shared__ __align__(16) float paL[4][2][M];  // L4 partials, 2 KB

    const int t  = threadIdx.x;
    const int l  = t & 63;
    const int wv = t >> 6;     // wave id: owns cols [64*wv, 64*wv+64)
    const int lr = l & 15;
    const int q  = l >> 4;

    float b1r[4], b2r[4], b3r[4], wmur[4][2];
    #pragma unroll
    for (int nt = 0; nt < 4; ++nt) {
        int col = 64*wv + 16*nt + lr;
        b1r[nt] = b1[col]; b2r[nt] = b2[col]; b3r[nt] = b3[col];
        wmur[nt][0] = wmu[2*col]; wmur[nt][1] = wmu[2*col + 1];
    }
    const float bm0 = bmu[0], bm1 = bmu[1];

    float px=0.f, py=0.f, wx=0.f, wy=0.f;
    float mx_s=-1e30f, sum_s=0.f, mx_r=-1e30f, sum_r=0.f;
    if (t < M) {
        int g = blockIdx.x*M + t;
        px = pos0[2*g]; py = pos0[2*g+1]; wx = wind[2*g]; wy = wind[2*g+1];
    }

    // C-layout writeback with relu + hi/lo split into swizzled hA
    auto writeback = [&](f32x4 (&a)[4][4]) {
        #pragma unroll
        for (int mt = 0; mt < 4; ++mt)
          #pragma unroll
          for (int nt = 0; nt < 4; ++nt)
            #pragma unroll
            for (int r = 0; r < 4; ++r) {
                float h = fmaxf(a[mt][nt][r], 0.f);
                f16 hi = (f16)h;
                f16 lo = (f16)(h - (float)hi);
                int row = 16*mt + 4*q + r;
                int col = 16*(4*wv + nt) + lr;
                int off = row*256 + (((col >> 3) ^ (row & 31)) << 3) + (col & 7);
                hA_hi[off] = hi;
                hA_lo[off] = lo;
            }
    };

    // 256-K GEMM: A = hA (all 64 rows), B = this wave's 64-col slice
    auto gemm256 = [&](const f16* Bh, const f16* Bl, const float (&br)[4],
                       f32x4 (&a)[4][4]) {
        #pragma unroll
        for (int mt = 0; mt < 4; ++mt)
          #pragma unroll
          for (int nt = 0; nt < 4; ++nt)
            a[mt][nt] = (f32x4){br[nt], br[nt], br[nt], br[nt]};
        #pragma unroll
        for (int kc = 0; kc < 8; ++kc) {
            f16x8 ah[4], al[4], bh[4], bl[4];
            #pragma unroll
            for (int mt = 0; mt < 4; ++mt) {
                int row = 16*mt + lr;
                int off = row*256 + (((kc*4 + q) ^ (row & 31)) << 3);
                ah[mt] = *(const f16x8*)(hA_hi + off);   // ds_read_b128
                al[mt] = *(const f16x8*)(hA_lo + off);
            }
            #pragma unroll
            for (int nt = 0; nt < 4; ++nt) {
                int widx = ((kc*16 + 4*wv + nt)*64 + l)*8;
                bh[nt] = *(const f16x8*)(Bh + widx);     // coalesced dwordx4
                bl[nt] = *(const f16x8*)(Bl + widx);
            }
            #pragma unroll
            for (int mt = 0; mt < 4; ++mt)
              #pragma unroll
              for (int nt = 0; nt < 4; ++nt)
                mfma3(a[mt][nt], ah[mt], al[mt], bh[nt], bl[nt]);
        }
    };

    for (int step = 0; step < HORIZON; ++step) {
        // ---- P0: obs -> obsA (overlaid at hA base, row stride 40 f16) ----
        if (t < M) {
            float o[16];
            float dx0 = px - 1.75f, dy0 = py - 1.75f;
            float dx1 = px - 1.75f, dy1 = py - 3.75f;
            float dx2 = px - 3.75f, dy2 = py - 2.00f;
            o[0] = px*0.1f;        o[1] = py*0.1f;
            o[2] = (4.f-px)*0.1f;  o[3] = (3.f-py)*0.1f;
            o[4] = -dx0*0.1f;      o[5] = -dy0*0.1f;
            o[6] = -dx1*0.1f;      o[7] = -dy1*0.1f;
            o[8] = -dx2*0.1f;      o[9] = -dy2*0.1f;
            o[10] = sqrtf(dx0*dx0+dy0*dy0+1e-9f) - 0.38f;
            o[11] = sqrtf(dx1*dx1+dy1*dy1+1e-9f) - 0.42f;
            o[12] = sqrtf(dx2*dx2+dy2*dy2+1e-9f) - 0.34f;
            o[13] = 0.f; o[14] = 0.f; o[15] = 0.f;
            #pragma unroll
            for (int k = 0; k < 32; ++k) {
                float v = (k < 16) ? o[k] : 0.f;
                f16 hi = (f16)v;
                hA_hi[t*40 + k] = hi;
                hA_lo[t*40 + k] = (f16)(v - (float)hi);
            }
        }
        __syncthreads();   // S1: obsA visible; prev-step paL reads done

        f32x4 acc[4][4];

        // ---- L1: obs(13 pad 32) -> 256 ----
        #pragma unroll
        for (int mt = 0; mt < 4; ++mt)
          #pragma unroll
          for (int nt = 0; nt < 4; ++nt)
            acc[mt][nt] = (f32x4){b1r[nt], b1r[nt], b1r[nt], b1r[nt]};
        {
            f16x8 ah[4], al[4], bh[4], bl[4];
            #pragma unroll
            for (int mt = 0; mt < 4; ++mt) {
                int off = (16*mt + lr)*40 + q*8;
                ah[mt] = *(const f16x8*)(hA_hi + off);
                al[mt] = *(const f16x8*)(hA_lo + off);
            }
            #pragma unroll
            for (int nt = 0; nt < 4; ++nt) {
                int widx = ((4*wv + nt)*64 + l)*8;
                bh[nt] = *(const f16x8*)(wp + W1H + widx);
                bl[nt] = *(const f16x8*)(wp + W1L + widx);
            }
            #pragma unroll
            for (int mt = 0; mt < 4; ++mt)
              #pragma unroll
              for (int nt = 0; nt < 4; ++nt)
                mfma3(acc[mt][nt], ah[mt], al[mt], bh[nt], bl[nt]);
        }
        __syncthreads();   // S2: obsA reads done
        writeback(acc);    // h1 -> hA
        __syncthreads();   // S3: h1 visible

        // ---- L2 ----
        gemm256(wp + W2H, wp + W2L, b2r, acc);
        __syncthreads();   // S4: h1 reads done
        writeback(acc);    // h2 -> hA
        __syncthreads();   // S5: h2 visible

        // ---- L3 + fused L4 (no h3 LDS round-trip) ----
        gemm256(wp + W3H, wp + W3L, b3r, acc);
        {
            float pa[4][4][2];
            #pragma unroll
            for (int mt = 0; mt < 4; ++mt)
              #pragma unroll
              for (int r = 0; r < 4; ++r)
                { pa[mt][r][0] = 0.f; pa[mt][r][1] = 0.f; }
            #pragma unroll
            for (int mt = 0; mt < 4; ++mt)
              #pragma unroll
              for (int nt = 0; nt < 4; ++nt)
                #pragma unroll
                for (int r = 0; r < 4; ++r) {
                    float h = fmaxf(acc[mt][nt][r], 0.f);
                    pa[mt][r][0] = fmaf(h, wmur[nt][0], pa[mt][r][0]);
                    pa[mt][r][1] = fmaf(h, wmur[nt][1], pa[mt][r][1]);
                }
            // butterfly over the 16 col-lanes (bits 0..3)
            #pragma unroll
            for (int s = 0; s < 4; ++s) {
                #pragma unroll
                for (int mt = 0; mt < 4; ++mt)
                  #pragma unroll
                  for (int r = 0; r < 4; ++r) {
                      pa[mt][r][0] += __shfl_xor(pa[mt][r][0], 1 << s, 64);
                      pa[mt][r][1] += __shfl_xor(pa[mt][r][1], 1 << s, 64);
                  }
            }
            if (lr == 0) {   // lane 0 of each quad writes its rows
                #pragma unroll
                for (int mt = 0; mt < 4; ++mt)
                  #pragma unroll
                  for (int c = 0; c < 2; ++c) {
                      f32x4 v = {pa[mt][0][c], pa[mt][1][c], pa[mt][2][c], pa[mt][3][c]};
                      *(f32x4*)&paL[wv][c][16*mt + 4*q] = v;
                  }
            }
        }
        __syncthreads();   // S6: paL visible; all hA reads done

        // ---- P5: action, dynamics, STREL ----
        if (t < M) {
            float s0 = bm0 + paL[0][0][t] + paL[1][0][t] + paL[2][0][t] + paL[3][0][t];
            float s1 = bm1 + paL[0][1][t] + paL[1][1][t] + paL[2][1][t] + paL[3][1][t];
            float ax = fminf(fmaxf(s0, -1.f), 1.f);
            float ay = fminf(fmaxf(s1, -1.f), 1.f);
            float vx = 2.f*ax + wx, vy = 2.f*ay + wy;
            #pragma unroll
            for (int s = 0; s < 4; ++s) {
                px = fminf(fmaxf(px + 0.0625f*vx, -4.f), 10.f);
                py = fminf(fmaxf(py + 0.0625f*vy, -4.f), 10.f);
            }
            float dx0 = px - 1.75f, dy0 = py - 1.75f;
            float dx1 = px - 1.75f, dy1 = py - 3.75f;
            float dx2 = px - 3.75f, dy2 = py - 2.00f;
            float c0 = sqrtf(dx0*dx0+dy0*dy0+1e-9f) - 0.38f;
            float c1 = sqrtf(dx1*dx1+dy1*dy1+1e-9f) - 0.42f;
            float c2 = sqrtf(dx2*dx2+dy2*dy2+1e-9f) - 0.34f;
            float cmin = fminf(c0, fminf(c1, c2));
            float ssum = expf(-50.f*(c0-cmin)) + expf(-50.f*(c1-cmin)) + expf(-50.f*(c2-cmin));
            float safe = cmin - logf(ssum)/50.f;
            float gdx = px - 4.f, gdy = py - 3.f;
            float reach = 0.45f - sqrtf(gdx*gdx+gdy*gdy+1e-9f);
            float xs = -8.f*safe;
            if (xs > mx_s) { sum_s = sum_s*expf(mx_s - xs) + 1.f; mx_s = xs; }
            else           { sum_s += expf(xs - mx_s); }
            float xr = 8.f*reach;
            if (xr > mx_r) { sum_r = sum_r*expf(mx_r - xr) + 1.f; mx_r = xr; }
            else           { sum_r += expf(xr - mx_r); }
        }
    }

    if (t < M) {
        float rs = -(mx_s + logf(sum_s)) * 0.125f;
        float rr =  (mx_r + logf(sum_r)) * 0.125f;
        float u0 = -8.f*rs, u1 = -8.f*rr;
        float mu = fmaxf(u0, u1);
        float rho = -(mu + logf(expf(u0-mu) + expf(u1-mu))) * 0.125f;
        out[blockIdx.x*M + t] = rho;
    }
}

} // namespace

extern "C" void kernel_launch(void* const* d_in, const int* in_sizes, int n_in,
                              void* d_out, int out_size, void* d_ws, size_t ws_size,
                              hipStream_t stream)
{
    const float* pos0 = (const float*)d_in[0];
    const float* wind = (const float*)d_in[1];
    const float* w1   = (const float*)d_in[2];
    const float* b1   = (const float*)d_in[3];
    const float* w2   = (const float*)d_in[4];
    const float* b2   = (const float*)d_in[5];
    const float* w3   = (const float*)d_in[6];
    const float* b3   = (const float*)d_in[7];
    const float* wmu  = (const float*)d_in[8];
    const float* bmu  = (const float*)d_in[9];
    float* out = (float*)d_out;
    f16* wp = (f16*)d_ws;   // 278528 f16 = 544 KB packed weights

    prep_kernel<<<544, 256, 0, stream>>>(w1, w2, w3, wp);

    const int B = in_sizes[0] / 2;     // 32768 agents
    const int blocks = B / M;          // 512 blocks, 2/CU
    rollout_kernel<<<blocks, NT, 0, stream>>>(pos0, wind, b1, b2, b3,
                                              wmu, bmu, wp, out);
}